// Round 1
// baseline (180.940 us; speedup 1.0000x reference)
//
#include <hip/hip_runtime.h>

// TermME actuarial projection, restructured:
//  - per-policy scan collapses to single state D with geometric decay
//  - all t-only quantities (discount, inflation*maint) precomputed in LDS
//  - monthly mortality table (1-(1-m)^(1/12)) precomputed in LDS (600 entries)
//  - mortality/lapse gathers hoisted to once per policy-year (dur, dur+1
//    selected per month by lane phase so t stays wave-uniform -> broadcast LDS)
//  - maturity handled by gating contributions with t < t_end
//  - deterministic two-kernel reduction (block partials in d_ws as double)

#define BLOCK 256
#define GRID 2048

__global__ __launch_bounds__(BLOCK) void term_proj_kernel(
    const float* __restrict__ premium_pp,
    const float* __restrict__ sum_assured,
    const float* __restrict__ policy_count,
    const float* __restrict__ mort_table,    // 100 x 6
    const float* __restrict__ disc_rate_ann, // 30
    const int*   __restrict__ duration_mth,
    const int*   __restrict__ age_at_entry,
    const int*   __restrict__ policy_term,
    double* __restrict__ partials,
    int n)
{
    __shared__ float  s_mortm[600];   // monthly mortality rates
    __shared__ float2 s_dm[240];      // {dv[t], 5*infl[t]*dv[t]}
    __shared__ float  s_lm[5];        // monthly lapse rates by min(dur,4)
    __shared__ float  s_red[BLOCK / 64];

    const int tid = threadIdx.x;
    const float tw = 1.0f / 12.0f;

    // ---- build LDS tables (once per block) ----
    for (int j = tid; j < 600; j += BLOCK)
        s_mortm[j] = 1.0f - powf(1.0f - mort_table[j], tw);
    for (int j = tid; j < 240; j += BLOCK) {
        float tf   = (float)j;
        float r    = disc_rate_ann[j / 12 + 1];
        float e    = tf * tw;
        float dv   = powf(1.0f + r, -e);
        float infl = powf(1.01f, e);
        s_dm[j] = make_float2(dv, 5.0f * infl * dv);
    }
    if (tid < 5) {
        float lr = fmaxf(0.1f - 0.02f * (float)tid, 0.02f);
        s_lm[tid] = 1.0f - powf(1.0f - lr, tw);
    }
    __syncthreads();

    float acc = 0.0f;
    const int G = GRID * BLOCK;
    for (int i = blockIdx.x * BLOCK + tid; i < n; i += G) {
        const float prem = premium_pp[i];
        const float sa   = sum_assured[i];
        const float pc   = policy_count[i];
        const int   dm0  = duration_mth[i];
        const int   age  = age_at_entry[i];
        const int   t_end = policy_term[i] * 12 - dm0;  // in [1,240]

        int d  = dm0 / 12;            // dur at t=0
        int ph = dm0 - d * 12;        // dm0 % 12
        int p  = (12 - ph) % 12;      // month-in-block where dur increments
        int p_eff = (p == 0) ? 100 : p;

        float D = pc;                 // pols_if_at_BEF_DECR at t=0
        // t=0 specials: commissions (=premiums) + acquisition expense, dv[0]=1
        if (dm0 == 0) acc -= fmaf(prem, pc, 300.0f * pc);

        for (int b = 0; b < 20; ++b) {
            // dur = d for months < p_eff, d+1 for months >= p_eff
            int   dcl = min(d, 5);
            float ql  = s_mortm[(age - 18 + d - dcl) * 6 + dcl];
            float lml = s_lm[min(d, 4)];
            float kl  = (1.0f - ql) * (1.0f - lml);
            float xl  = fmaf(-sa, ql, prem);

            int   d1  = d + 1;
            int   dch = min(d1, 5);
            float qh  = s_mortm[(age - 18 + d1 - dch) * 6 + dch];
            float lmh = s_lm[min(d1, 4)];
            float kh  = (1.0f - qh) * (1.0f - lmh);
            float xh  = fmaf(-sa, qh, prem);

            #pragma unroll
            for (int m = 0; m < 12; ++m) {
                const int t = 12 * b + m;          // wave-uniform
                const bool hi = (m >= p_eff);
                float x = hi ? xh : xl;
                float k = hi ? kh : kl;
                float2 dd = s_dm[t];               // broadcast read
                float f1 = fmaf(x, dd.x, -dd.y);   // (prem - SA*q)*dv - mdv
                f1 = (t < t_end) ? f1 : 0.0f;      // maturity / horizon gate
                acc = fmaf(D, f1, acc);
                D *= k;
            }
            d = d1;
            if (__all(12 * (b + 1) >= t_end)) break;
        }
    }

    // ---- block reduction ----
    for (int off = 32; off > 0; off >>= 1)
        acc += __shfl_down(acc, off, 64);
    if ((tid & 63) == 0) s_red[tid >> 6] = acc;
    __syncthreads();
    if (tid == 0) {
        float bsum = 0.0f;
        #pragma unroll
        for (int w = 0; w < BLOCK / 64; ++w) bsum += s_red[w];
        partials[blockIdx.x] = (double)bsum;
    }
}

__global__ __launch_bounds__(256) void term_reduce_kernel(
    const double* __restrict__ partials, int nb, float* __restrict__ out)
{
    __shared__ double s_red[4];
    double s = 0.0;
    for (int j = threadIdx.x; j < nb; j += 256) s += partials[j];
    for (int off = 32; off > 0; off >>= 1)
        s += __shfl_down(s, off, 64);
    if ((threadIdx.x & 63) == 0) s_red[threadIdx.x >> 6] = s;
    __syncthreads();
    if (threadIdx.x == 0)
        out[0] = (float)(s_red[0] + s_red[1] + s_red[2] + s_red[3]);
}

extern "C" void kernel_launch(void* const* d_in, const int* in_sizes, int n_in,
                              void* d_out, int out_size, void* d_ws, size_t ws_size,
                              hipStream_t stream) {
    const float* premium_pp    = (const float*)d_in[0];
    const float* sum_assured   = (const float*)d_in[1];
    const float* policy_count  = (const float*)d_in[2];
    const float* mort_table    = (const float*)d_in[3];
    const float* disc_rate_ann = (const float*)d_in[4];
    const int*   duration_mth  = (const int*)d_in[5];
    const int*   age_at_entry  = (const int*)d_in[6];
    const int*   policy_term   = (const int*)d_in[7];
    const int n = in_sizes[0];

    double* partials = (double*)d_ws;
    term_proj_kernel<<<GRID, BLOCK, 0, stream>>>(
        premium_pp, sum_assured, policy_count, mort_table, disc_rate_ann,
        duration_mth, age_at_entry, policy_term, partials, n);
    term_reduce_kernel<<<1, 256, 0, stream>>>(partials, GRID, (float*)d_out);
}

// Round 2
// 156.112 us; speedup vs baseline: 1.1590x; 1.1590x over previous
//
#include <hip/hip_runtime.h>

// TermME actuarial projection, policy-year-aligned restructure:
//  - maturity always lands on a policy-year boundary -> iterate {partial
//    chunk of p months, then full 12-month years}; q/lapse/x/k are
//    loop-invariant registers within each chunk (no per-month selects)
//  - maturity gate is once-per-year D=(y<Y)?D:0 (dead lanes carry D=0)
//  - 4-month Horner fold: acc += D*(f0+k*f1+k^2*f2+k^3*f3); D *= k^4
//  - t-only tables (discount, 5*infl*disc) in LDS as float2[256];
//    monthly mortality (600) and monthly lapse (5) in LDS
//  - single kernel; block partial -> float atomicAdd into d_out
//    (threshold is ~3.3e9, atomic ordering noise ~1e5)

#define BLOCK 256
#define GRID 2048

__global__ __launch_bounds__(BLOCK) void term_proj_kernel(
    const float* __restrict__ premium_pp,
    const float* __restrict__ sum_assured,
    const float* __restrict__ policy_count,
    const float* __restrict__ mort_table,    // 100 x 6
    const float* __restrict__ disc_rate_ann, // 30
    const int*   __restrict__ duration_mth,
    const int*   __restrict__ age_at_entry,
    const int*   __restrict__ policy_term,
    float* __restrict__ out,
    int n)
{
    __shared__ float  s_mortm[600];   // monthly mortality rates
    __shared__ float2 s_dm[256];      // {dv[t], 5*infl[t]*dv[t]}
    __shared__ float  s_lm[8];        // monthly lapse by min(dur,4)
    __shared__ float  s_red[BLOCK / 64];

    const int tid = threadIdx.x;
    const float tw = 1.0f / 12.0f;

    // ---- build LDS tables (once per block) ----
    for (int j = tid; j < 600; j += BLOCK)
        s_mortm[j] = 1.0f - powf(1.0f - mort_table[j], tw);
    for (int j = tid; j < 256; j += BLOCK) {
        float e    = (float)j * tw;
        float r    = disc_rate_ann[j / 12 + 1];
        float dv   = powf(1.0f + r, -e);
        float infl = powf(1.01f, e);
        s_dm[j] = make_float2(dv, 5.0f * infl * dv);
    }
    if (tid < 8) {
        float lr = fmaxf(0.1f - 0.02f * (float)min(tid, 4), 0.02f);
        s_lm[tid] = 1.0f - powf(1.0f - lr, tw);
    }
    __syncthreads();

    float acc = 0.0f;
    const int G = GRID * BLOCK;
    for (int i = blockIdx.x * BLOCK + tid; i < n; i += G) {
        const float prem = premium_pp[i];
        const float sa   = sum_assured[i];
        const float pc   = policy_count[i];
        const int   dm0  = duration_mth[i];
        const int   age  = age_at_entry[i];
        const int   term = policy_term[i];

        const int d0     = dm0 / 12;
        const int ph     = dm0 - d0 * 12;
        const int p      = ph ? (12 - ph) : 0;   // partial-chunk length
        const int dfirst = d0 + (ph ? 1 : 0);
        const int Y      = term - dfirst;        // # of full-year chunks

        float D = pc;
        // t=0 specials when dm0==0: commissions(=premiums) + acq expense, dv=1
        if (dm0 == 0) acc -= fmaf(prem, pc, 300.0f * pc);

        // ---- partial chunk: months t=0..p-1 at dur=d0 ----
        if (__any(p > 0)) {
            int   dc = min(d0, 5);
            float q  = s_mortm[(age - 18 + d0 - dc) * 6 + dc];
            float lm = s_lm[min(d0, 4)];
            float k  = (1.0f - q) * (1.0f - lm);
            float x  = fmaf(-sa, q, prem);
            #pragma unroll
            for (int m = 0; m < 12; ++m) {
                float2 dd = s_dm[m];             // uniform broadcast
                float  f  = fmaf(x, dd.x, -dd.y);
                bool live = (m < p);
                acc = fmaf(D, live ? f : 0.0f, acc);
                D *= (live ? k : 1.0f);
            }
        }

        // ---- full policy-year chunks ----
        const int t0 = p;
        for (int y = 0; y < 20; ++y) {
            if (__all(y >= Y)) break;
            int   d  = dfirst + y;
            int   dc = min(d, 5);
            float q  = s_mortm[(age - 18 + d - dc) * 6 + dc];
            float lm = s_lm[min(d, 4)];
            float k  = (1.0f - q) * (1.0f - lm);
            float x  = fmaf(-sa, q, prem);
            D = (y < Y) ? D : 0.0f;              // maturity gate (per year)
            float k2 = k * k;
            float k4 = k2 * k2;
            const float2* dmp = &s_dm[t0 + 12 * y];
            #pragma unroll
            for (int g = 0; g < 3; ++g) {
                float2 v0 = dmp[4 * g + 0];
                float2 v1 = dmp[4 * g + 1];
                float2 v2 = dmp[4 * g + 2];
                float2 v3 = dmp[4 * g + 3];
                float f0 = fmaf(x, v0.x, -v0.y);
                float f1 = fmaf(x, v1.x, -v1.y);
                float f2 = fmaf(x, v2.x, -v2.y);
                float f3 = fmaf(x, v3.x, -v3.y);
                float h  = fmaf(k, f3, f2);
                h = fmaf(k, h, f1);
                h = fmaf(k, h, f0);              // f0 + k f1 + k^2 f2 + k^3 f3
                acc = fmaf(D, h, acc);
                D *= k4;
            }
        }
    }

    // ---- block reduction -> one float atomic per block ----
    for (int off = 32; off > 0; off >>= 1)
        acc += __shfl_down(acc, off, 64);
    if ((tid & 63) == 0) s_red[tid >> 6] = acc;
    __syncthreads();
    if (tid == 0) {
        float bsum = 0.0f;
        #pragma unroll
        for (int w = 0; w < BLOCK / 64; ++w) bsum += s_red[w];
        atomicAdd(out, bsum);
    }
}

extern "C" void kernel_launch(void* const* d_in, const int* in_sizes, int n_in,
                              void* d_out, int out_size, void* d_ws, size_t ws_size,
                              hipStream_t stream) {
    const float* premium_pp    = (const float*)d_in[0];
    const float* sum_assured   = (const float*)d_in[1];
    const float* policy_count  = (const float*)d_in[2];
    const float* mort_table    = (const float*)d_in[3];
    const float* disc_rate_ann = (const float*)d_in[4];
    const int*   duration_mth  = (const int*)d_in[5];
    const int*   age_at_entry  = (const int*)d_in[6];
    const int*   policy_term   = (const int*)d_in[7];
    const int n = in_sizes[0];

    hipMemsetAsync(d_out, 0, sizeof(float), stream);
    term_proj_kernel<<<GRID, BLOCK, 0, stream>>>(
        premium_pp, sum_assured, policy_count, mort_table, disc_rate_ann,
        duration_mth, age_at_entry, policy_term, (float*)d_out, n);
}

// Round 3
// 126.972 us; speedup vs baseline: 1.4250x; 1.2295x over previous
//
#include <hip/hip_runtime.h>

// TermME actuarial projection, round 3: block-local counting sort by
// remaining-months to eliminate dead-lane drag in the year loop.
//  - rem = term*12 - dm0 in [1,240]; block sorts its 2048-policy window
//    by rem into a packed 16B/policy LDS array (histogram + scan + scatter,
//    all coalesced global reads; sort is LDS-only)
//  - compute pass walks sorted records: wave lanes share rem +/-4 ->
//    year-loop trip count ~= lane average (was wave max ~20)
//  - per policy-year: q/lapse/x/k loop-invariant, 4-month Horner folds
//  - maturity gate once per year; t-only tables (disc, 5*infl*disc) in LDS
//  - per-block float partial -> atomicAdd(d_out)

#define BLOCK 512
#define WIN   2048
#define KPT   (WIN / BLOCK)   // 4 policies per thread

__global__ __launch_bounds__(BLOCK, 8) void term_proj_kernel(
    const float* __restrict__ premium_pp,
    const float* __restrict__ sum_assured,
    const float* __restrict__ policy_count,
    const float* __restrict__ mort_table,    // 100 x 6
    const float* __restrict__ disc_rate_ann, // 30
    const int*   __restrict__ duration_mth,
    const int*   __restrict__ age_at_entry,
    const int*   __restrict__ policy_term,
    float* __restrict__ out,
    int n)
{
    __shared__ float  s_mortm[600];   // monthly mortality rates
    __shared__ float2 s_dm[240];      // {dv[t], 5*infl[t]*dv[t]}
    __shared__ float  s_lm[8];        // monthly lapse by min(dur,4)
    __shared__ float4 s_data[WIN];    // sorted {prem, sa, pc, packed}
    __shared__ int    s_hist[256];    // rem-1 histogram
    __shared__ int    s_scan[256];    // exclusive offsets -> scatter cursors
    __shared__ float  s_red[BLOCK / 64];

    const int tid   = threadIdx.x;
    const int base  = blockIdx.x * WIN;
    const int count = min(WIN, n - base);
    const float tw  = 1.0f / 12.0f;

    // ---- build t-tables ----
    for (int j = tid; j < 600; j += BLOCK)
        s_mortm[j] = 1.0f - powf(1.0f - mort_table[j], tw);
    for (int j = tid; j < 240; j += BLOCK) {
        float e    = (float)j * tw;
        float r    = disc_rate_ann[j / 12 + 1];
        float dv   = powf(1.0f + r, -e);
        float infl = powf(1.01f, e);
        s_dm[j] = make_float2(dv, 5.0f * infl * dv);
    }
    if (tid < 8) {
        float lr = fmaxf(0.1f - 0.02f * (float)min(tid, 4), 0.02f);
        s_lm[tid] = 1.0f - powf(1.0f - lr, tw);
    }
    if (tid < 256) s_hist[tid] = 0;
    __syncthreads();

    // ---- pass 1: histogram of key = rem-1 (coalesced) ----
    #pragma unroll
    for (int k = 0; k < KPT; ++k) {
        int l = tid + k * BLOCK;
        if (l < count) {
            int i   = base + l;
            int key = policy_term[i] * 12 - duration_mth[i] - 1; // 0..239
            atomicAdd(&s_hist[key], 1);
        }
    }
    __syncthreads();

    // ---- exclusive scan (shift + Hillis-Steele inclusive) ----
    if (tid < 256) s_scan[tid] = (tid > 0) ? s_hist[tid - 1] : 0;
    __syncthreads();
    for (int off = 1; off < 256; off <<= 1) {
        int v = 0;
        if (tid < 256) { v = s_scan[tid]; if (tid >= off) v += s_scan[tid - off]; }
        __syncthreads();
        if (tid < 256) s_scan[tid] = v;
        __syncthreads();
    }

    // ---- pass 2: coalesced gather -> sorted LDS scatter ----
    #pragma unroll
    for (int k = 0; k < KPT; ++k) {
        int l = tid + k * BLOCK;
        if (l < count) {
            int i    = base + l;
            int dm0  = duration_mth[i];
            int term = policy_term[i];
            int age  = age_at_entry[i];
            int key  = term * 12 - dm0 - 1;
            int pos  = atomicAdd(&s_scan[key], 1);
            unsigned pk = (unsigned)dm0 | ((unsigned)age << 8) | ((unsigned)term << 16);
            s_data[pos] = make_float4(premium_pp[i], sum_assured[i],
                                      policy_count[i], __uint_as_float(pk));
        }
    }
    __syncthreads();

    // ---- compute pass over sorted records ----
    float acc = 0.0f;
    #pragma unroll 1
    for (int k = 0; k < KPT; ++k) {
        int j = tid + k * BLOCK;   // wave lanes contiguous in sorted order
        if (j >= count) continue;
        float4 v = s_data[j];
        const float prem = v.x, sa = v.y, pc = v.z;
        const unsigned pk = __float_as_uint(v.w);
        const int dm0  = pk & 255;
        const int age  = (pk >> 8) & 255;
        const int term = pk >> 16;

        const int d0     = dm0 / 12;
        const int ph     = dm0 - d0 * 12;
        const int p      = ph ? (12 - ph) : 0;   // partial-chunk length
        const int dfirst = d0 + (ph ? 1 : 0);
        const int Y      = term - dfirst;        // # of full-year chunks

        float D = pc;
        if (dm0 == 0) acc -= fmaf(prem, pc, 300.0f * pc);

        // partial chunk: months 0..p-1 at dur=d0
        if (__any(p > 0)) {
            int   dc = min(d0, 5);
            float q  = s_mortm[(age - 18 + d0 - dc) * 6 + dc];
            float lm = s_lm[min(d0, 4)];
            float kk = (1.0f - q) * (1.0f - lm);
            float x  = fmaf(-sa, q, prem);
            #pragma unroll
            for (int m = 0; m < 12; ++m) {
                float2 dd = s_dm[m];
                float  f  = fmaf(x, dd.x, -dd.y);
                bool live = (m < p);
                acc = fmaf(D, live ? f : 0.0f, acc);
                D *= (live ? kk : 1.0f);
            }
        }

        // full policy-year chunks
        for (int y = 0; y < 20; ++y) {
            if (__all(y >= Y)) break;
            int   d  = dfirst + y;
            int   dc = min(d, 5);
            float q  = s_mortm[(age - 18 + d - dc) * 6 + dc];
            float lm = s_lm[min(d, 4)];
            float kk = (1.0f - q) * (1.0f - lm);
            float x  = fmaf(-sa, q, prem);
            D = (y < Y) ? D : 0.0f;              // maturity gate
            float k2 = kk * kk;
            float k4 = k2 * k2;
            const float2* dmp = &s_dm[p + 12 * y];
            #pragma unroll
            for (int g = 0; g < 3; ++g) {
                float2 v0 = dmp[4 * g + 0];
                float2 v1 = dmp[4 * g + 1];
                float2 v2 = dmp[4 * g + 2];
                float2 v3 = dmp[4 * g + 3];
                float f0 = fmaf(x, v0.x, -v0.y);
                float f1 = fmaf(x, v1.x, -v1.y);
                float f2 = fmaf(x, v2.x, -v2.y);
                float f3 = fmaf(x, v3.x, -v3.y);
                float h  = fmaf(kk, f3, f2);
                h = fmaf(kk, h, f1);
                h = fmaf(kk, h, f0);
                acc = fmaf(D, h, acc);
                D *= k4;
            }
        }
    }

    // ---- block reduction -> one float atomic per block ----
    for (int off = 32; off > 0; off >>= 1)
        acc += __shfl_down(acc, off, 64);
    if ((tid & 63) == 0) s_red[tid >> 6] = acc;
    __syncthreads();
    if (tid == 0) {
        float bsum = 0.0f;
        #pragma unroll
        for (int w = 0; w < BLOCK / 64; ++w) bsum += s_red[w];
        atomicAdd(out, bsum);
    }
}

extern "C" void kernel_launch(void* const* d_in, const int* in_sizes, int n_in,
                              void* d_out, int out_size, void* d_ws, size_t ws_size,
                              hipStream_t stream) {
    const float* premium_pp    = (const float*)d_in[0];
    const float* sum_assured   = (const float*)d_in[1];
    const float* policy_count  = (const float*)d_in[2];
    const float* mort_table    = (const float*)d_in[3];
    const float* disc_rate_ann = (const float*)d_in[4];
    const int*   duration_mth  = (const int*)d_in[5];
    const int*   age_at_entry  = (const int*)d_in[6];
    const int*   policy_term   = (const int*)d_in[7];
    const int n = in_sizes[0];

    hipMemsetAsync(d_out, 0, sizeof(float), stream);
    const int grid = (n + WIN - 1) / WIN;
    term_proj_kernel<<<grid, BLOCK, 0, stream>>>(
        premium_pp, sum_assured, policy_count, mort_table, disc_rate_ann,
        duration_mth, age_at_entry, policy_term, (float*)d_out, n);
}

// Round 5
// 120.526 us; speedup vs baseline: 1.5013x; 1.0535x over previous
//
#include <hip/hip_runtime.h>

// TermME round 4 (resubmit; round 4 hit GPUAcquisitionTimeout, never ran):
// halve LDS month-traffic via dv-only table.
//  - mdv[t] = dv[t] * 5 * 1.01^(t/12); the inflation factor is a register
//    geometric recurrence (e *= 1.01 per policy year, c = 1.01^(1/12))
//  - per policy-year: acc += D*x*S1 - D*e*S2, S1 = Horner(k; dv[12]),
//    S2 = Horner(k*c; dv[12]) -- 12 x ds_read_b32 (broadcast after sort)
//  - block-local counting sort by rem = term*12 - dm0 (as round 3);
//    sorted lanes share p = rem%12 -> partial chunk breaks after ~p iters
//  - per-block float partial -> atomicAdd(d_out)

#define BLOCK 512
#define WIN   2048
#define KPT   (WIN / BLOCK)   // 4 policies per thread

__global__ __launch_bounds__(BLOCK, 8) void term_proj_kernel(
    const float* __restrict__ premium_pp,
    const float* __restrict__ sum_assured,
    const float* __restrict__ policy_count,
    const float* __restrict__ mort_table,    // 100 x 6
    const float* __restrict__ disc_rate_ann, // 30
    const int*   __restrict__ duration_mth,
    const int*   __restrict__ age_at_entry,
    const int*   __restrict__ policy_term,
    float* __restrict__ out,
    int n)
{
    __shared__ float  s_mortm[600];   // monthly mortality rates
    __shared__ float  s_dv[240];      // discount factor per month
    __shared__ float  s_lmm[8];       // (1 - monthly lapse) by min(dur,4)
    __shared__ float  s_cp[12];       // 5 * c^p
    __shared__ float4 s_data[WIN];    // sorted {prem, sa, pc, packed}
    __shared__ int    s_hist[256];
    __shared__ int    s_scan[256];
    __shared__ float  s_red[BLOCK / 64];

    const int tid   = threadIdx.x;
    const int base  = blockIdx.x * WIN;
    const int count = min(WIN, n - base);
    const float tw  = 1.0f / 12.0f;
    const float c   = powf(1.01f, tw);       // monthly inflation factor

    // ---- build LDS tables ----
    for (int j = tid; j < 600; j += BLOCK)
        s_mortm[j] = 1.0f - powf(1.0f - mort_table[j], tw);
    for (int j = tid; j < 240; j += BLOCK)
        s_dv[j] = powf(1.0f + disc_rate_ann[j / 12 + 1], -(float)j * tw);
    if (tid < 8) {
        float lr = fmaxf(0.1f - 0.02f * (float)min(tid, 4), 0.02f);
        s_lmm[tid] = powf(1.0f - lr, tw);    // (1-lapse_rate)^(1/12)
    }
    if (tid < 12) s_cp[tid] = 5.0f * powf(1.01f, (float)tid * tw);
    if (tid < 256) s_hist[tid] = 0;
    __syncthreads();

    // ---- counting sort by key = rem-1 ----
    #pragma unroll
    for (int k = 0; k < KPT; ++k) {
        int l = tid + k * BLOCK;
        if (l < count) {
            int i   = base + l;
            int key = policy_term[i] * 12 - duration_mth[i] - 1; // 0..239
            atomicAdd(&s_hist[key], 1);
        }
    }
    __syncthreads();
    if (tid < 256) s_scan[tid] = (tid > 0) ? s_hist[tid - 1] : 0;
    __syncthreads();
    for (int off = 1; off < 256; off <<= 1) {
        int v = 0;
        if (tid < 256) { v = s_scan[tid]; if (tid >= off) v += s_scan[tid - off]; }
        __syncthreads();
        if (tid < 256) s_scan[tid] = v;
        __syncthreads();
    }
    #pragma unroll
    for (int k = 0; k < KPT; ++k) {
        int l = tid + k * BLOCK;
        if (l < count) {
            int i    = base + l;
            int dm0  = duration_mth[i];
            int term = policy_term[i];
            int age  = age_at_entry[i];
            int key  = term * 12 - dm0 - 1;
            int pos  = atomicAdd(&s_scan[key], 1);
            unsigned pk = (unsigned)dm0 | ((unsigned)age << 8) | ((unsigned)term << 16);
            s_data[pos] = make_float4(premium_pp[i], sum_assured[i],
                                      policy_count[i], __uint_as_float(pk));
        }
    }
    __syncthreads();

    // ---- compute over sorted records ----
    float acc = 0.0f;
    #pragma unroll 1
    for (int kk = 0; kk < KPT; ++kk) {
        int j = tid + kk * BLOCK;
        if (j >= count) continue;
        float4 v = s_data[j];
        const float prem = v.x, sa = v.y, pc = v.z;
        const unsigned pk = __float_as_uint(v.w);
        const int dm0  = pk & 255;
        const int age  = (pk >> 8) & 255;
        const int term = (int)(pk >> 16);

        const int d0     = dm0 / 12;
        const int ph     = dm0 - d0 * 12;
        const int p      = ph ? (12 - ph) : 0;   // live months in partial chunk
        const int dfirst = d0 + (ph ? 1 : 0);
        const int Y      = term - dfirst;        // full-year chunks

        float D = pc;
        if (dm0 == 0) acc -= fmaf(prem, pc, 300.0f * pc);

        // ---- partial chunk: months 0..p-1 at dur=d0 (p near-uniform) ----
        {
            int   dc = min(d0, 5);
            float q  = s_mortm[(age - 18 + d0 - dc) * 6 + dc];
            float k1 = (1.0f - q) * s_lmm[min(d0, 4)];
            float x  = fmaf(-sa, q, prem);
            float ep = 5.0f;                     // 5 * c^t at t=0
            #pragma unroll 1
            for (int m = 0; m < 12; ++m) {
                if (__all(m >= p)) break;
                float f = (x - ep) * s_dv[m];
                bool live = m < p;
                acc = fmaf(D, live ? f : 0.0f, acc);
                D *= (live ? k1 : 1.0f);
                ep *= c;
            }
        }

        // ---- full policy-year chunks ----
        float e = s_cp[p];                       // 5 * c^(t at first full year)
        #pragma unroll 1
        for (int y = 0; y < 20; ++y) {
            if (__all(y >= Y)) break;
            int   d  = dfirst + y;
            int   dc = min(d, 5);
            float q  = s_mortm[(age - 18 + d - dc) * 6 + dc];
            float k1 = (1.0f - q) * s_lmm[min(d, 4)];
            float x  = fmaf(-sa, q, prem);
            D = (y < Y) ? D : 0.0f;              // maturity gate
            float kc  = k1 * c;
            const float* bp = &s_dv[p + 12 * y]; // near-broadcast reads
            float a0 = bp[0],  a1 = bp[1],  a2 = bp[2],  a3 = bp[3];
            float a4 = bp[4],  a5 = bp[5],  a6 = bp[6],  a7 = bp[7];
            float a8 = bp[8],  a9 = bp[9],  a10 = bp[10], a11 = bp[11];
            float S1 = a11, S2 = a11;
            S1 = fmaf(k1, S1, a10); S2 = fmaf(kc, S2, a10);
            S1 = fmaf(k1, S1, a9);  S2 = fmaf(kc, S2, a9);
            S1 = fmaf(k1, S1, a8);  S2 = fmaf(kc, S2, a8);
            S1 = fmaf(k1, S1, a7);  S2 = fmaf(kc, S2, a7);
            S1 = fmaf(k1, S1, a6);  S2 = fmaf(kc, S2, a6);
            S1 = fmaf(k1, S1, a5);  S2 = fmaf(kc, S2, a5);
            S1 = fmaf(k1, S1, a4);  S2 = fmaf(kc, S2, a4);
            S1 = fmaf(k1, S1, a3);  S2 = fmaf(kc, S2, a3);
            S1 = fmaf(k1, S1, a2);  S2 = fmaf(kc, S2, a2);
            S1 = fmaf(k1, S1, a1);  S2 = fmaf(kc, S2, a1);
            S1 = fmaf(k1, S1, a0);  S2 = fmaf(kc, S2, a0);
            acc = fmaf(D * x, S1, acc);
            acc = fmaf(-(D * e), S2, acc);
            // D *= k1^12
            float k2 = k1 * k1, k4 = k2 * k2, k8 = k4 * k4;
            D *= k8 * k4;
            e *= 1.01f;                          // c^12 exactly
        }
    }

    // ---- block reduction -> one float atomic per block ----
    for (int off = 32; off > 0; off >>= 1)
        acc += __shfl_down(acc, off, 64);
    if ((tid & 63) == 0) s_red[tid >> 6] = acc;
    __syncthreads();
    if (tid == 0) {
        float bsum = 0.0f;
        #pragma unroll
        for (int w = 0; w < BLOCK / 64; ++w) bsum += s_red[w];
        atomicAdd(out, bsum);
    }
}

extern "C" void kernel_launch(void* const* d_in, const int* in_sizes, int n_in,
                              void* d_out, int out_size, void* d_ws, size_t ws_size,
                              hipStream_t stream) {
    const float* premium_pp    = (const float*)d_in[0];
    const float* sum_assured   = (const float*)d_in[1];
    const float* policy_count  = (const float*)d_in[2];
    const float* mort_table    = (const float*)d_in[3];
    const float* disc_rate_ann = (const float*)d_in[4];
    const int*   duration_mth  = (const int*)d_in[5];
    const int*   age_at_entry  = (const int*)d_in[6];
    const int*   policy_term   = (const int*)d_in[7];
    const int n = in_sizes[0];

    hipMemsetAsync(d_out, 0, sizeof(float), stream);
    const int grid = (n + WIN - 1) / WIN;
    term_proj_kernel<<<grid, BLOCK, 0, stream>>>(
        premium_pp, sum_assured, policy_count, mort_table, disc_rate_ann,
        duration_mth, age_at_entry, policy_term, (float*)d_out, n);
}